// Round 4
// baseline (667.105 us; speedup 1.0000x reference)
//
#include <hip/hip_runtime.h>
#include <hip/hip_bf16.h>

typedef unsigned short u16;
typedef short s16x8 __attribute__((ext_vector_type(8)));
typedef unsigned int u32x2 __attribute__((ext_vector_type(2)));
typedef float f32x4 __attribute__((ext_vector_type(4)));

#define F_DIM 2048
#define A_DIM 1024
#define H_DIM 1024
#define BATCH 128
#define LLEN  196
#define MROWS (BATCH * LLEN)   // 25088
#define MTILES (MROWS / 256)   // 98

__device__ __forceinline__ u16 f2b(float x) {
  union { float f; unsigned int u; } c; c.f = x;
  unsigned int r = (c.u + 0x7fffu + ((c.u >> 16) & 1u)) >> 16;  // RNE
  return (u16)r;
}

__device__ __forceinline__ unsigned int f2b_pk(float a, float b) {
  unsigned int r;
  asm volatile("v_cvt_pk_bf16_f32 %0, %1, %2" : "=v"(r) : "v"(a), "v"(b));
  return r;
}

__device__ __forceinline__ void gload_lds16(const void* g, void* l) {
  __builtin_amdgcn_global_load_lds((const __attribute__((address_space(1))) void*)g,
                                   (__attribute__((address_space(3))) void*)l, 16, 0, 0);
}

// ---------------------------------------------------------------------------
// K0: W_enc (2048x1024 fp32, k-major) -> WT (1024x2048 bf16, a-major)
__global__ void wenc_cvt_kernel(const float* __restrict__ W, u16* __restrict__ WT) {
  __shared__ float tile[32][33];
  int kb = blockIdx.x * 32, ab = blockIdx.y * 32;
  int t = threadIdx.x;
  int r = t >> 3, c = (t & 7) * 4;
  float4 v = *(const float4*)&W[(size_t)(kb + r) * A_DIM + ab + c];
  tile[r][c] = v.x; tile[r][c + 1] = v.y; tile[r][c + 2] = v.z; tile[r][c + 3] = v.w;
  __syncthreads();
  ushort4 o;
  o.x = f2b(tile[c + 0][r]);
  o.y = f2b(tile[c + 1][r]);
  o.z = f2b(tile[c + 2][r]);
  o.w = f2b(tile[c + 3][r]);
  *(ushort4*)&WT[(size_t)(ab + r) * F_DIM + kb + c] = o;
}

// ---------------------------------------------------------------------------
// K1: attn2p[b][a] = hidden[b]·W_hid[:,a] + b_hid[a] + b_enc[a]  (k-split 8,
// atomic). ROUND-0 form restored: the round-3 non-atomic version (128 blocks,
// K=1024 in-block) was 2 waves/CU latency-exposed, ~+100 us regression.
__global__ void attn2_kernel(const float* __restrict__ hidden, const float* __restrict__ W_hid,
                             const float* __restrict__ b_hid, const float* __restrict__ b_enc,
                             float* __restrict__ attn2p) {
  __shared__ float hl[8][128];
  int t = threadIdx.x;
  int a  = blockIdx.x * 256 + t;
  int b0 = blockIdx.y * 8;
  int k0 = blockIdx.z * 128;
  {
    int j = t >> 5, kk = (t & 31) * 4;
    float4 v = *(const float4*)&hidden[(size_t)(b0 + j) * H_DIM + k0 + kk];
    hl[j][kk + 0] = v.x; hl[j][kk + 1] = v.y; hl[j][kk + 2] = v.z; hl[j][kk + 3] = v.w;
  }
  __syncthreads();
  float acc[8] = {0.f, 0.f, 0.f, 0.f, 0.f, 0.f, 0.f, 0.f};
  #pragma unroll 4
  for (int k = 0; k < 128; ++k) {
    float w = W_hid[(size_t)(k0 + k) * A_DIM + a];
    #pragma unroll
    for (int j = 0; j < 8; ++j) acc[j] = fmaf(hl[j][k], w, acc[j]);
  }
  if (blockIdx.z == 0) {
    float bias = b_hid[a] + b_enc[a];
    #pragma unroll
    for (int j = 0; j < 8; ++j) acc[j] += bias;
  }
  #pragma unroll
  for (int j = 0; j < 8; ++j) atomicAdd(&attn2p[(size_t)(b0 + j) * A_DIM + a], acc[j]);
}

// ---------------------------------------------------------------------------
// K2: fused GEMM + score. BM=BN=256, BK=64, 8 waves (2M x 4N), wave 128x64.
// One K-tile per 4-phase group; ping-pong A reg sets. ROUND-4 changes:
//  (1) loads-first/writes-last group order: p0 {BGL(T+1), ALD lo(T+2)},
//      p1 {ALD hi(T+2)}, p2 {AWR lo(T+1)}, p3 {AWR hi(T+1), vmcnt(8)}.
//      A-load -> ds_write lead = 6 phases (~4000cyc >> 900 HBM); implicit
//      waits are vmcnt(16)/vmcnt(12); only explicit gate is vmcnt(8) on B
//      (WT is L2/L3-resident, 3-phase lead ample). No short wait anywhere.
//  (2) B fragments cached across mh (bf0 read p0, used p0+p2; bf1 read p1,
//      used p1+p3): per-tile LDS reads 32 -> 24 b128/wave.
// T2 XOR swizzle on both tiles (granule ^= row&7): conflict-free b128.
__global__ __launch_bounds__(512, 2) void gemm_score(
    const float* __restrict__ enc, const u16* __restrict__ WT,
    const float* __restrict__ attn2p, const float* __restrict__ W_full,
    float* __restrict__ scores) {
  __shared__ __align__(16) u16 As[2 * 16384];   // 2 bufs x 256 x 64 bf16 = 64 KB
  __shared__ __align__(16) u16 Bs[2 * 16384];   // 64 KB

  int i = blockIdx.x;
  int g = i >> 5, r = i & 31;
  int y = r >> 3, gi = r & 7;
  int mt = g * 8 + gi;
  if (mt >= MTILES) return;              // uniform per-block: no barrier hazard
  int m0 = mt * 256, n0 = y * 256;
  int t = threadIdx.x;
  int lane = t & 63, wave = t >> 6;
  int wr = wave >> 2, wc = wave & 3;     // wave grid 2M x 4N
  int c16 = lane & 15, quad = lane >> 4;

  // A loads: thread covers row t>>2 (of a 128-row half), 4 sites of 4 floats.
  const float* aP = enc + (size_t)(m0 + (t >> 2)) * F_DIM + (t & 3) * 4;
  // A ds_write offsets (b64 each), XOR key (row)&7 on 16B granules.
  int awo[4];
  #pragma unroll
  for (int s = 0; s < 4; ++s)
    awo[s] = (t >> 2) * 64 + ((t & 3) & 1) * 4
           + (((s * 2 + ((t & 3) >> 1)) ^ ((t >> 2) & 7)) * 8);
  // B gload_lds: site s covers rows s*64 + (t>>3); source granule pre-swizzled.
  const u16* bgp = WT + (size_t)(n0 + (t >> 3)) * F_DIM + ((t & 7) ^ ((t >> 3) & 7)) * 8;

  // fragment read offsets (u16 elems)
  const int akey = c16 & 7;
  int gsw[2];
  gsw[0] = ((0 * 4 + quad) ^ akey) * 8;
  gsw[1] = ((1 * 4 + quad) ^ akey) * 8;
  const int aro = (wr * 128 + c16) * 64;
  const int bro = (wc * 64 + c16) * 64;

  f32x4 acc[8][4];
  #pragma unroll
  for (int mi = 0; mi < 8; ++mi)
    #pragma unroll
    for (int ni = 0; ni < 4; ++ni) acc[mi][ni] = (f32x4){0.f, 0.f, 0.f, 0.f};

  s16x8 af[4][2], bf0[2][2], bf1[2][2];
  float4 R0lo[4], R0hi[4], R1lo[4], R1hi[4];   // ping-pong A reg sets

#define ALD(RX, half, kt_) do {                                                 \
    const float* p_ = aP + (size_t)(half) * 128 * F_DIM + (kt_) * 64;           \
    RX[0] = *(const float4*)(p_);                                               \
    RX[1] = *(const float4*)(p_ + 16);                                          \
    RX[2] = *(const float4*)(p_ + 32);                                          \
    RX[3] = *(const float4*)(p_ + 48);                                          \
  } while (0)

#define AWR(RX, cb, half) do {                                                  \
    _Pragma("unroll")                                                           \
    for (int s_ = 0; s_ < 4; ++s_) {                                            \
      u32x2 w_; w_.x = f2b_pk(RX[s_].x, RX[s_].y);                              \
      w_.y = f2b_pk(RX[s_].z, RX[s_].w);                                        \
      *(u32x2*)&As[(cb) * 16384 + (half) * 8192 + awo[s_]] = w_;                \
    }                                                                           \
  } while (0)

#define BGL(cb, kt_) do {                                                       \
    _Pragma("unroll")                                                           \
    for (int s_ = 0; s_ < 4; ++s_)                                              \
      gload_lds16(bgp + (size_t)s_ * 64 * F_DIM + (size_t)(kt_) * 64,           \
                  Bs + (cb) * 16384 + s_ * 4096 + wave * 512);                  \
  } while (0)

#define DSRA(cb, mh)                                                            \
    _Pragma("unroll")                                                           \
    for (int i_ = 0; i_ < 4; ++i_)                                              \
      _Pragma("unroll")                                                         \
      for (int h_ = 0; h_ < 2; ++h_)                                            \
        af[i_][h_] = *(const s16x8*)&As[(cb) * 16384 + aro                      \
                                        + ((mh) * 4 + i_) * 1024 + gsw[h_]];

#define DSRB(BF, cb, nh)                                                        \
    _Pragma("unroll")                                                           \
    for (int j_ = 0; j_ < 2; ++j_)                                              \
      _Pragma("unroll")                                                         \
      for (int h_ = 0; h_ < 2; ++h_)                                            \
        BF[j_][h_] = *(const s16x8*)&Bs[(cb) * 16384 + bro                      \
                                        + ((nh) * 2 + j_) * 1024 + gsw[h_]];

#define PHTAIL(BF, mh, nh) do {                                                 \
    __builtin_amdgcn_s_barrier();                                               \
    asm volatile("s_waitcnt lgkmcnt(0)" ::: "memory");                          \
    __builtin_amdgcn_s_setprio(1);                                              \
    _Pragma("unroll")                                                           \
    for (int i_ = 0; i_ < 4; ++i_)                                              \
      _Pragma("unroll")                                                         \
      for (int j_ = 0; j_ < 2; ++j_)                                            \
        _Pragma("unroll")                                                       \
        for (int h_ = 0; h_ < 2; ++h_)                                          \
          acc[(mh) * 4 + i_][(nh) * 2 + j_] =                                   \
              __builtin_amdgcn_mfma_f32_16x16x32_bf16(                          \
                  af[i_][h_], BF[j_][h_],                                       \
                  acc[(mh) * 4 + i_][(nh) * 2 + j_], 0, 0, 0);                  \
    __builtin_amdgcn_s_setprio(0);                                              \
    __builtin_amdgcn_s_barrier();                                               \
  } while (0)

// Group T: MFMA on buf RB_, stage tile T+1 into WB_ (W-set = A(T+1), loaded
// in group T-1), load L-set with A(T+2). Loads first, writes last.
#define GROUP(T_, RB_, WB_, WLO_, WHI_, LLO_, LHI_) do {                        \
    int kB_ = min((T_) + 1, 31);                                                \
    int kA_ = min((T_) + 2, 31);                                                \
    /* p0 */                                                                    \
    DSRA(RB_, 0); DSRB(bf0, RB_, 0);                                            \
    BGL(WB_, kB_);                                                              \
    ALD(LLO_, 0, kA_);                                                          \
    PHTAIL(bf0, 0, 0);                                                          \
    /* p1 */                                                                    \
    DSRB(bf1, RB_, 1);                                                          \
    ALD(LHI_, 1, kA_);                                                          \
    PHTAIL(bf1, 0, 1);                                                          \
    /* p2 */                                                                    \
    DSRA(RB_, 1);                                                               \
    AWR(WLO_, WB_, 0);                                                          \
    PHTAIL(bf0, 1, 0);                                                          \
    /* p3 */                                                                    \
    AWR(WHI_, WB_, 1);                                                          \
    asm volatile("s_waitcnt vmcnt(8)" ::: "memory");                            \
    PHTAIL(bf1, 1, 1);                                                          \
  } while (0)

  // ---- prologue: buf0 <- A(0),B(0); R1 <- A(1). Exit invariant: 8
  // outstanding vmem = {R1lo, R1hi} = A(1), W-set for group 0.
  ALD(R0lo, 0, 0);
  ALD(R0hi, 1, 0);
  BGL(0, 0);
  asm volatile("s_waitcnt vmcnt(4)" ::: "memory");   // R0 done; BGL(0) in flight
  AWR(R0lo, 0, 0);
  AWR(R0hi, 0, 1);
  ALD(R1lo, 0, 1);
  ALD(R1hi, 1, 1);
  asm volatile("s_waitcnt vmcnt(8) lgkmcnt(0)" ::: "memory");  // drain BGL(0)
  __builtin_amdgcn_s_barrier();

  // ---- main loop: 32 K-tiles, 4 phases each; static buf/set via unroll-2.
  #pragma unroll 1
  for (int T = 0; T < 32; T += 2) {
    GROUP(T,     0, 1, R1lo, R1hi, R0lo, R0hi);
    GROUP(T + 1, 1, 0, R0lo, R0hi, R1lo, R1hi);
  }
#undef GROUP
#undef PHTAIL
#undef DSRA
#undef DSRB
#undef BGL
#undef AWR
#undef ALD

  // ---- epilogue: relu(attn1 + attn2)·W_full, 16-lane reduce, atomic score.
  int bfirst = m0 / LLEN;                       // block rows span <= 3 batches
  int bnd1 = (bfirst + 1) * LLEN, bnd2 = (bfirst + 2) * LLEN;
  int b1c = min(bfirst + 1, BATCH - 1), b2c = min(bfirst + 2, BATCH - 1);
  float wf[4], a2v0[4], a2v1[4], a2v2[4];
  #pragma unroll
  for (int ni = 0; ni < 4; ++ni) {
    int col = n0 + wc * 64 + ni * 16 + c16;
    wf[ni]   = W_full[col];
    a2v0[ni] = attn2p[(size_t)bfirst * A_DIM + col];
    a2v1[ni] = attn2p[(size_t)b1c * A_DIM + col];
    a2v2[ni] = attn2p[(size_t)b2c * A_DIM + col];
  }
  #pragma unroll
  for (int mi = 0; mi < 8; ++mi) {
    #pragma unroll
    for (int rr = 0; rr < 4; ++rr) {
      int row_g = m0 + wr * 128 + mi * 16 + quad * 4 + rr;
      float p = 0.f;
      #pragma unroll
      for (int ni = 0; ni < 4; ++ni) {
        float a2 = row_g >= bnd1 ? (row_g >= bnd2 ? a2v2[ni] : a2v1[ni]) : a2v0[ni];
        float v = acc[mi][ni][rr] + a2;
        v = fmaxf(v, 0.f);
        p = fmaf(v, wf[ni], p);
      }
      p += __shfl_xor(p, 1);
      p += __shfl_xor(p, 2);
      p += __shfl_xor(p, 4);
      p += __shfl_xor(p, 8);
      if (c16 == 0) atomicAdd(&scores[row_g], p);
    }
  }
}

// ---------------------------------------------------------------------------
// K3: softmax over L=196 per batch row (b_full dropped: softmax-invariant)
__global__ void softmax_kernel(const float* __restrict__ scores, float* __restrict__ alpha) {
  __shared__ float red[8];
  int b = blockIdx.x, t = threadIdx.x;
  float s = (t < LLEN) ? scores[b * LLEN + t] : -3.0e38f;
  float m = s;
  #pragma unroll
  for (int o = 1; o <= 32; o <<= 1) m = fmaxf(m, __shfl_xor(m, o));
  if ((t & 63) == 0) red[t >> 6] = m;
  __syncthreads();
  m = fmaxf(fmaxf(red[0], red[1]), fmaxf(red[2], red[3]));
  float e = (t < LLEN) ? expf(s - m) : 0.f;
  float sum = e;
  #pragma unroll
  for (int o = 1; o <= 32; o <<= 1) sum += __shfl_xor(sum, o);
  __syncthreads();
  if ((t & 63) == 0) red[4 + (t >> 6)] = sum;
  __syncthreads();
  sum = red[4] + red[5] + red[6] + red[7];
  if (t < LLEN) alpha[b * LLEN + t] = e / sum;
}

// ---------------------------------------------------------------------------
// K4: context. Grid (8, 128) = 1024 blocks. Block owns (b, f-chunk of 256
// floats). f4 = t&63, l-quarter t>>6 (49 rows each); LDS 4-way reduce;
// exact-once enc read, direct store, no memset, no atomics.
__global__ __launch_bounds__(256) void context_kernel(
    const float* __restrict__ enc, const float* __restrict__ alpha,
    float* __restrict__ out) {
  __shared__ float al[LLEN];
  __shared__ float4 part[4][64];
  int b = blockIdx.y, t = threadIdx.x;
  if (t < LLEN) al[t] = alpha[b * LLEN + t];
  __syncthreads();
  int f4 = blockIdx.x * 64 + (t & 63);
  int lq = t >> 6;                 // 0..3, 49 L-rows each
  const float4* e4 = (const float4*)enc
                   + ((size_t)b * LLEN + lq * 49) * (F_DIM / 4) + f4;
  float4 acc = {0.f, 0.f, 0.f, 0.f};
  #pragma unroll 7
  for (int j = 0; j < 49; ++j) {
    float4 v = e4[(size_t)j * (F_DIM / 4)];
    float a = al[lq * 49 + j];
    acc.x = fmaf(v.x, a, acc.x);
    acc.y = fmaf(v.y, a, acc.y);
    acc.z = fmaf(v.z, a, acc.z);
    acc.w = fmaf(v.w, a, acc.w);
  }
  part[lq][t & 63] = acc;
  __syncthreads();
  if (t < 64) {
    float4 p0 = part[0][t], p1 = part[1][t], p2 = part[2][t], p3 = part[3][t];
    float4 s;
    s.x = (p0.x + p1.x) + (p2.x + p3.x);
    s.y = (p0.y + p1.y) + (p2.y + p3.y);
    s.z = (p0.z + p1.z) + (p2.z + p3.z);
    s.w = (p0.w + p1.w) + (p2.w + p3.w);
    *(float4*)(out + (size_t)b * F_DIM + (size_t)(blockIdx.x * 64 + t) * 4) = s;
  }
}

// ---------------------------------------------------------------------------
extern "C" void kernel_launch(void* const* d_in, const int* in_sizes, int n_in,
                              void* d_out, int out_size, void* d_ws, size_t ws_size,
                              hipStream_t stream) {
  const float* enc    = (const float*)d_in[0];
  const float* hidden = (const float*)d_in[1];
  const float* W_enc  = (const float*)d_in[2];
  const float* b_enc  = (const float*)d_in[3];
  const float* W_hid  = (const float*)d_in[4];
  const float* b_hid  = (const float*)d_in[5];
  const float* W_full = (const float*)d_in[6];
  float* out = (float*)d_out;
  float* alpha_out = out + (size_t)BATCH * F_DIM;

  const size_t wt_bytes = (size_t)A_DIM * F_DIM * sizeof(u16);     // 4 MB
  const size_t a2_bytes = (size_t)BATCH * A_DIM * sizeof(float);   // 512 KB
  const size_t sc_bytes = (size_t)MROWS * sizeof(float);           // 100 KB
  char* ws = (char*)d_ws;
  u16*   WT     = (u16*)ws;
  float* attn2p = (float*)(ws + wt_bytes);
  float* scores = (float*)(ws + wt_bytes + a2_bytes);

  // attn2p and scores are contiguous: single memset (attn2 + gemm epilogue
  // accumulate atomically).
  hipMemsetAsync(attn2p, 0, a2_bytes + sc_bytes, stream);

  wenc_cvt_kernel<<<dim3(F_DIM / 32, A_DIM / 32), 256, 0, stream>>>(W_enc, WT);
  attn2_kernel<<<dim3(A_DIM / 256, BATCH / 8, H_DIM / 128), 256, 0, stream>>>(hidden, W_hid, b_hid, b_enc, attn2p);
  gemm_score<<<dim3(416), 512, 0, stream>>>(enc, WT, attn2p, W_full, scores);
  softmax_kernel<<<dim3(BATCH), 256, 0, stream>>>(scores, alpha_out);
  context_kernel<<<dim3(8, BATCH), 256, 0, stream>>>(enc, alpha_out, out);
}

// Round 5
// 503.639 us; speedup vs baseline: 1.3246x; 1.3246x over previous
//
#include <hip/hip_runtime.h>
#include <hip/hip_bf16.h>

typedef unsigned short u16;
typedef short s16x8 __attribute__((ext_vector_type(8)));
typedef unsigned int u32x2 __attribute__((ext_vector_type(2)));
typedef float f32x4 __attribute__((ext_vector_type(4)));

#define F_DIM 2048
#define A_DIM 1024
#define H_DIM 1024
#define BATCH 128
#define LLEN  196
#define MROWS (BATCH * LLEN)   // 25088
#define MTILES (MROWS / 256)   // 98

__device__ __forceinline__ u16 f2b(float x) {
  union { float f; unsigned int u; } c; c.f = x;
  unsigned int r = (c.u + 0x7fffu + ((c.u >> 16) & 1u)) >> 16;  // RNE
  return (u16)r;
}

__device__ __forceinline__ unsigned int f2b_pk(float a, float b) {
  unsigned int r;
  asm volatile("v_cvt_pk_bf16_f32 %0, %1, %2" : "=v"(r) : "v"(a), "v"(b));
  return r;
}

__device__ __forceinline__ void gload_lds16(const void* g, void* l) {
  __builtin_amdgcn_global_load_lds((const __attribute__((address_space(1))) void*)g,
                                   (__attribute__((address_space(3))) void*)l, 16, 0, 0);
}

// ---------------------------------------------------------------------------
// K0: fused prep. Blocks [0,2048): W_enc (2048x1024 fp32, k-major) -> WT
// (1024x2048 bf16, a-major). Blocks [2048,2560): attn2p[b][a] =
// hidden[b]·W_hid[:,a] + b_hid[a] + b_enc[a] (k-split 8, atomic — the
// round-0 form; the non-atomic K=1024 version was a ~100us regression).
__global__ __launch_bounds__(256) void prep_kernel(
    const float* __restrict__ W, u16* __restrict__ WT,
    const float* __restrict__ hidden, const float* __restrict__ W_hid,
    const float* __restrict__ b_hid, const float* __restrict__ b_enc,
    float* __restrict__ attn2p) {
  int t = threadIdx.x;
  if (blockIdx.x < 2048) {
    __shared__ float tile[32][33];
    int id = blockIdx.x;
    int kb = (id & 63) * 32, ab = (id >> 6) * 32;
    int r = t >> 3, c = (t & 7) * 4;
    float4 v = *(const float4*)&W[(size_t)(kb + r) * A_DIM + ab + c];
    tile[r][c] = v.x; tile[r][c + 1] = v.y; tile[r][c + 2] = v.z; tile[r][c + 3] = v.w;
    __syncthreads();
    ushort4 o;
    o.x = f2b(tile[c + 0][r]);
    o.y = f2b(tile[c + 1][r]);
    o.z = f2b(tile[c + 2][r]);
    o.w = f2b(tile[c + 3][r]);
    *(ushort4*)&WT[(size_t)(ab + r) * F_DIM + kb + c] = o;
  } else {
    __shared__ float hl[8][128];
    int id = blockIdx.x - 2048;        // 512 blocks: 4 a-chunks x 16 b x 8 k
    int a  = (id & 3) * 256 + t;
    int b0 = ((id >> 2) & 15) * 8;
    int k0 = (id >> 6) * 128;
    {
      int j = t >> 5, kk = (t & 31) * 4;
      float4 v = *(const float4*)&hidden[(size_t)(b0 + j) * H_DIM + k0 + kk];
      hl[j][kk + 0] = v.x; hl[j][kk + 1] = v.y; hl[j][kk + 2] = v.z; hl[j][kk + 3] = v.w;
    }
    __syncthreads();
    float acc[8] = {0.f, 0.f, 0.f, 0.f, 0.f, 0.f, 0.f, 0.f};
    #pragma unroll 4
    for (int k = 0; k < 128; ++k) {
      float w = W_hid[(size_t)(k0 + k) * A_DIM + a];
      #pragma unroll
      for (int j = 0; j < 8; ++j) acc[j] = fmaf(hl[j][k], w, acc[j]);
    }
    if ((id >> 6) == 0) {
      float bias = b_hid[a] + b_enc[a];
      #pragma unroll
      for (int j = 0; j < 8; ++j) acc[j] += bias;
    }
    #pragma unroll
    for (int j = 0; j < 8; ++j) atomicAdd(&attn2p[(size_t)(b0 + j) * A_DIM + a], acc[j]);
  }
}

// ---------------------------------------------------------------------------
// K2: fused GEMM + score. BM=BN=256, BK=64, 8 waves (2M x 4N), wave 128x64.
// One K-tile per 4-phase group; ping-pong A reg sets. ROUND-5:
//  - NO cross-phase B-fragment cache (round-4's bf0/bf1 pushed allocation
//    past the 128-VGPR cap -> 230 MB/dispatch scratch spill; WRITE_SIZE 6MB
//    -> 237MB was the smoking gun). bf is transient per phase again.
//  - loads-first / writes-last group order (costs 0 registers):
//      p0 {DSR, BGL(T+1), ALD lo(T+2)}   p1 {DSR, ALD hi(T+2), AWR lo(T+1)}
//      p2 {DSR, AWR hi(T+1)}             p3 {DSR, vmcnt(8)}
//    FIFO trace: AWR lo waits implicit vmcnt(16), AWR hi vmcnt(12) — both
//    5-phase leads (~3500cyc >> 900 HBM). Explicit vmcnt(8) gates only B
//    (L2-resident WT, 3-phase lead). No wait shorter than its producer.
// T2 XOR swizzle on both tiles (granule ^= row&7): conflict-free b128.
__global__ __launch_bounds__(512, 2) void gemm_score(
    const float* __restrict__ enc, const u16* __restrict__ WT,
    const float* __restrict__ attn2p, const float* __restrict__ W_full,
    float* __restrict__ scores) {
  __shared__ __align__(16) u16 As[2 * 16384];   // 2 bufs x 256 x 64 bf16 = 64 KB
  __shared__ __align__(16) u16 Bs[2 * 16384];   // 64 KB

  int i = blockIdx.x;
  int g = i >> 5, r = i & 31;
  int y = r >> 3, gi = r & 7;
  int mt = g * 8 + gi;
  if (mt >= MTILES) return;              // uniform per-block: no barrier hazard
  int m0 = mt * 256, n0 = y * 256;
  int t = threadIdx.x;
  int lane = t & 63, wave = t >> 6;
  int wr = wave >> 2, wc = wave & 3;     // wave grid 2M x 4N
  int c16 = lane & 15, quad = lane >> 4;

  // A loads: thread covers row t>>2 (of a 128-row half), 4 sites of 4 floats.
  const float* aP = enc + (size_t)(m0 + (t >> 2)) * F_DIM + (t & 3) * 4;
  // A ds_write offsets (b64 each), XOR key (row)&7 on 16B granules.
  int awo[4];
  #pragma unroll
  for (int s = 0; s < 4; ++s)
    awo[s] = (t >> 2) * 64 + ((t & 3) & 1) * 4
           + (((s * 2 + ((t & 3) >> 1)) ^ ((t >> 2) & 7)) * 8);
  // B gload_lds: site s covers rows s*64 + (t>>3); source granule pre-swizzled.
  const u16* bgp = WT + (size_t)(n0 + (t >> 3)) * F_DIM + ((t & 7) ^ ((t >> 3) & 7)) * 8;

  // fragment read offsets (u16 elems)
  const int akey = c16 & 7;
  int gsw[2];
  gsw[0] = ((0 * 4 + quad) ^ akey) * 8;
  gsw[1] = ((1 * 4 + quad) ^ akey) * 8;
  const int aro = (wr * 128 + c16) * 64;
  const int bro = (wc * 64 + c16) * 64;

  f32x4 acc[8][4];
  #pragma unroll
  for (int mi = 0; mi < 8; ++mi)
    #pragma unroll
    for (int ni = 0; ni < 4; ++ni) acc[mi][ni] = (f32x4){0.f, 0.f, 0.f, 0.f};

  s16x8 af[4][2], bf[2][2];
  float4 R0lo[4], R0hi[4], R1lo[4], R1hi[4];   // ping-pong A reg sets

#define ALD(RX, half, kt_) do {                                                 \
    const float* p_ = aP + (size_t)(half) * 128 * F_DIM + (kt_) * 64;           \
    RX[0] = *(const float4*)(p_);                                               \
    RX[1] = *(const float4*)(p_ + 16);                                          \
    RX[2] = *(const float4*)(p_ + 32);                                          \
    RX[3] = *(const float4*)(p_ + 48);                                          \
  } while (0)

#define AWR(RX, cb, half) do {                                                  \
    _Pragma("unroll")                                                           \
    for (int s_ = 0; s_ < 4; ++s_) {                                            \
      u32x2 w_; w_.x = f2b_pk(RX[s_].x, RX[s_].y);                              \
      w_.y = f2b_pk(RX[s_].z, RX[s_].w);                                        \
      *(u32x2*)&As[(cb) * 16384 + (half) * 8192 + awo[s_]] = w_;                \
    }                                                                           \
  } while (0)

#define BGL(cb, kt_) do {                                                       \
    _Pragma("unroll")                                                           \
    for (int s_ = 0; s_ < 4; ++s_)                                              \
      gload_lds16(bgp + (size_t)s_ * 64 * F_DIM + (size_t)(kt_) * 64,           \
                  Bs + (cb) * 16384 + s_ * 4096 + wave * 512);                  \
  } while (0)

#define DSRA(cb, mh)                                                            \
    _Pragma("unroll")                                                           \
    for (int i_ = 0; i_ < 4; ++i_)                                              \
      _Pragma("unroll")                                                         \
      for (int h_ = 0; h_ < 2; ++h_)                                            \
        af[i_][h_] = *(const s16x8*)&As[(cb) * 16384 + aro                      \
                                        + ((mh) * 4 + i_) * 1024 + gsw[h_]];

#define DSRB(cb, nh)                                                            \
    _Pragma("unroll")                                                           \
    for (int j_ = 0; j_ < 2; ++j_)                                              \
      _Pragma("unroll")                                                         \
      for (int h_ = 0; h_ < 2; ++h_)                                            \
        bf[j_][h_] = *(const s16x8*)&Bs[(cb) * 16384 + bro                      \
                                        + ((nh) * 2 + j_) * 1024 + gsw[h_]];

#define PHTAIL(mh, nh) do {                                                     \
    __builtin_amdgcn_s_barrier();                                               \
    asm volatile("s_waitcnt lgkmcnt(0)" ::: "memory");                          \
    __builtin_amdgcn_s_setprio(1);                                              \
    _Pragma("unroll")                                                           \
    for (int i_ = 0; i_ < 4; ++i_)                                              \
      _Pragma("unroll")                                                         \
      for (int j_ = 0; j_ < 2; ++j_)                                            \
        _Pragma("unroll")                                                       \
        for (int h_ = 0; h_ < 2; ++h_)                                          \
          acc[(mh) * 4 + i_][(nh) * 2 + j_] =                                   \
              __builtin_amdgcn_mfma_f32_16x16x32_bf16(                          \
                  af[i_][h_], bf[j_][h_],                                       \
                  acc[(mh) * 4 + i_][(nh) * 2 + j_], 0, 0, 0);                  \
    __builtin_amdgcn_s_setprio(0);                                              \
    __builtin_amdgcn_s_barrier();                                               \
  } while (0)

// Group T: MFMA on buf RB_, stage tile T+1 into WB_ (W-set = A(T+1), loaded
// in group T-1), load L-set with A(T+2). Loads first, writes last.
#define GROUP(T_, RB_, WB_, WLO_, WHI_, LLO_, LHI_) do {                        \
    int kB_ = min((T_) + 1, 31);                                                \
    int kA_ = min((T_) + 2, 31);                                                \
    /* p0 */                                                                    \
    DSRA(RB_, 0); DSRB(RB_, 0);                                                 \
    BGL(WB_, kB_);                                                              \
    ALD(LLO_, 0, kA_);                                                          \
    PHTAIL(0, 0);                                                               \
    /* p1 */                                                                    \
    DSRB(RB_, 1);                                                               \
    ALD(LHI_, 1, kA_);                                                          \
    AWR(WLO_, WB_, 0);                                                          \
    PHTAIL(0, 1);                                                               \
    /* p2 */                                                                    \
    DSRA(RB_, 1); DSRB(RB_, 0);                                                 \
    AWR(WHI_, WB_, 1);                                                          \
    PHTAIL(1, 0);                                                               \
    /* p3 */                                                                    \
    DSRB(RB_, 1);                                                               \
    asm volatile("s_waitcnt vmcnt(8)" ::: "memory");                            \
    PHTAIL(1, 1);                                                               \
  } while (0)

  // ---- prologue: buf0 <- A(0),B(0); R1 <- A(1). Exit invariant: 8
  // outstanding vmem = {R1lo, R1hi} = A(1), W-set for group 0.
  ALD(R0lo, 0, 0);
  ALD(R0hi, 1, 0);
  BGL(0, 0);
  asm volatile("s_waitcnt vmcnt(4)" ::: "memory");   // R0 done; BGL(0) in flight
  AWR(R0lo, 0, 0);
  AWR(R0hi, 0, 1);
  ALD(R1lo, 0, 1);
  ALD(R1hi, 1, 1);
  asm volatile("s_waitcnt vmcnt(8) lgkmcnt(0)" ::: "memory");  // drain BGL(0)
  __builtin_amdgcn_s_barrier();

  // ---- main loop: 32 K-tiles, 4 phases each; static buf/set via unroll-2.
  #pragma unroll 1
  for (int T = 0; T < 32; T += 2) {
    GROUP(T,     0, 1, R1lo, R1hi, R0lo, R0hi);
    GROUP(T + 1, 1, 0, R0lo, R0hi, R1lo, R1hi);
  }
#undef GROUP
#undef PHTAIL
#undef DSRA
#undef DSRB
#undef BGL
#undef AWR
#undef ALD

  // ---- epilogue: relu(attn1 + attn2)·W_full, 16-lane reduce, atomic score.
  int bfirst = m0 / LLEN;                       // block rows span <= 3 batches
  int bnd1 = (bfirst + 1) * LLEN, bnd2 = (bfirst + 2) * LLEN;
  int b1c = min(bfirst + 1, BATCH - 1), b2c = min(bfirst + 2, BATCH - 1);
  float wf[4], a2v0[4], a2v1[4], a2v2[4];
  #pragma unroll
  for (int ni = 0; ni < 4; ++ni) {
    int col = n0 + wc * 64 + ni * 16 + c16;
    wf[ni]   = W_full[col];
    a2v0[ni] = attn2p[(size_t)bfirst * A_DIM + col];
    a2v1[ni] = attn2p[(size_t)b1c * A_DIM + col];
    a2v2[ni] = attn2p[(size_t)b2c * A_DIM + col];
  }
  #pragma unroll
  for (int mi = 0; mi < 8; ++mi) {
    #pragma unroll
    for (int rr = 0; rr < 4; ++rr) {
      int row_g = m0 + wr * 128 + mi * 16 + quad * 4 + rr;
      float p = 0.f;
      #pragma unroll
      for (int ni = 0; ni < 4; ++ni) {
        float a2 = row_g >= bnd1 ? (row_g >= bnd2 ? a2v2[ni] : a2v1[ni]) : a2v0[ni];
        float v = acc[mi][ni][rr] + a2;
        v = fmaxf(v, 0.f);
        p = fmaf(v, wf[ni], p);
      }
      p += __shfl_xor(p, 1);
      p += __shfl_xor(p, 2);
      p += __shfl_xor(p, 4);
      p += __shfl_xor(p, 8);
      if (c16 == 0) atomicAdd(&scores[row_g], p);
    }
  }
}

// ---------------------------------------------------------------------------
// K4: fused softmax + context. Grid (8, 128). Each block recomputes the
// 196-wide softmax for its batch row from scores (cheap, removes a kernel +
// a dependency stage); block x==0 writes alpha_out. Context: block owns
// (b, f-chunk of 256 floats); f4 = t&63, l-quarter t>>6; LDS 4-way reduce;
// exact-once enc read, direct store, no memset, no atomics.
__global__ __launch_bounds__(256) void context_kernel(
    const float* __restrict__ enc, const float* __restrict__ scores,
    float* __restrict__ alpha_out, float* __restrict__ out) {
  __shared__ float al[LLEN];
  __shared__ float red[8];
  __shared__ float4 part[4][64];
  int b = blockIdx.y, t = threadIdx.x;
  // softmax over scores[b, 0..195]
  float s = (t < LLEN) ? scores[b * LLEN + t] : -3.0e38f;
  float m = s;
  #pragma unroll
  for (int o = 1; o <= 32; o <<= 1) m = fmaxf(m, __shfl_xor(m, o));
  if ((t & 63) == 0) red[t >> 6] = m;
  __syncthreads();
  m = fmaxf(fmaxf(red[0], red[1]), fmaxf(red[2], red[3]));
  float e = (t < LLEN) ? expf(s - m) : 0.f;
  float sum = e;
  #pragma unroll
  for (int o = 1; o <= 32; o <<= 1) sum += __shfl_xor(sum, o);
  if ((t & 63) == 0) red[4 + (t >> 6)] = sum;
  __syncthreads();
  sum = red[4] + red[5] + red[6] + red[7];
  float av = e / sum;
  if (t < LLEN) {
    al[t] = av;
    if (blockIdx.x == 0) alpha_out[b * LLEN + t] = av;
  }
  __syncthreads();
  // context
  int f4 = blockIdx.x * 64 + (t & 63);
  int lq = t >> 6;                 // 0..3, 49 L-rows each
  const float4* e4 = (const float4*)enc
                   + ((size_t)b * LLEN + lq * 49) * (F_DIM / 4) + f4;
  float4 acc = {0.f, 0.f, 0.f, 0.f};
  #pragma unroll 7
  for (int j = 0; j < 49; ++j) {
    float4 v = e4[(size_t)j * (F_DIM / 4)];
    float a = al[lq * 49 + j];
    acc.x = fmaf(v.x, a, acc.x);
    acc.y = fmaf(v.y, a, acc.y);
    acc.z = fmaf(v.z, a, acc.z);
    acc.w = fmaf(v.w, a, acc.w);
  }
  part[lq][t & 63] = acc;
  __syncthreads();
  if (t < 64) {
    float4 p0 = part[0][t], p1 = part[1][t], p2 = part[2][t], p3 = part[3][t];
    float4 sv;
    sv.x = (p0.x + p1.x) + (p2.x + p3.x);
    sv.y = (p0.y + p1.y) + (p2.y + p3.y);
    sv.z = (p0.z + p1.z) + (p2.z + p3.z);
    sv.w = (p0.w + p1.w) + (p2.w + p3.w);
    *(float4*)(out + (size_t)b * F_DIM + (size_t)(blockIdx.x * 64 + t) * 4) = sv;
  }
}

// ---------------------------------------------------------------------------
extern "C" void kernel_launch(void* const* d_in, const int* in_sizes, int n_in,
                              void* d_out, int out_size, void* d_ws, size_t ws_size,
                              hipStream_t stream) {
  const float* enc    = (const float*)d_in[0];
  const float* hidden = (const float*)d_in[1];
  const float* W_enc  = (const float*)d_in[2];
  const float* b_enc  = (const float*)d_in[3];
  const float* W_hid  = (const float*)d_in[4];
  const float* b_hid  = (const float*)d_in[5];
  const float* W_full = (const float*)d_in[6];
  float* out = (float*)d_out;
  float* alpha_out = out + (size_t)BATCH * F_DIM;

  const size_t wt_bytes = (size_t)A_DIM * F_DIM * sizeof(u16);     // 4 MB
  const size_t a2_bytes = (size_t)BATCH * A_DIM * sizeof(float);   // 512 KB
  const size_t sc_bytes = (size_t)MROWS * sizeof(float);           // 100 KB
  char* ws = (char*)d_ws;
  u16*   WT     = (u16*)ws;
  float* attn2p = (float*)(ws + wt_bytes);
  float* scores = (float*)(ws + wt_bytes + a2_bytes);

  // attn2p and scores are contiguous: single memset (both accumulated
  // atomically).
  hipMemsetAsync(attn2p, 0, a2_bytes + sc_bytes, stream);

  prep_kernel<<<dim3(2048 + 512), 256, 0, stream>>>(W_enc, WT, hidden, W_hid, b_hid, b_enc, attn2p);
  // 13 groups x 32 (4 n-tiles x 8 m-tiles); guard kills mt >= 98.
  gemm_score<<<dim3(416), 512, 0, stream>>>(enc, WT, attn2p, W_full, scores);
  context_kernel<<<dim3(8, BATCH), 256, 0, stream>>>(enc, scores, alpha_out, out);
}

// Round 6
// 470.916 us; speedup vs baseline: 1.4166x; 1.0695x over previous
//
#include <hip/hip_runtime.h>
#include <hip/hip_bf16.h>

typedef unsigned short u16;
typedef short s16x8 __attribute__((ext_vector_type(8)));
typedef unsigned int u32x2 __attribute__((ext_vector_type(2)));
typedef unsigned int u32x4 __attribute__((ext_vector_type(4)));
typedef float f32x4 __attribute__((ext_vector_type(4)));

#define F_DIM 2048
#define A_DIM 1024
#define H_DIM 1024
#define BATCH 128
#define LLEN  196
#define MROWS (BATCH * LLEN)   // 25088
#define MTILES (MROWS / 256)   // 98

__device__ __forceinline__ u16 f2b(float x) {
  union { float f; unsigned int u; } c; c.f = x;
  unsigned int r = (c.u + 0x7fffu + ((c.u >> 16) & 1u)) >> 16;  // RNE
  return (u16)r;
}

__device__ __forceinline__ unsigned int f2b_pk(float a, float b) {
  unsigned int r;
  asm volatile("v_cvt_pk_bf16_f32 %0, %1, %2" : "=v"(r) : "v"(a), "v"(b));
  return r;
}

__device__ __forceinline__ void gload_lds16(const void* g, void* l) {
  __builtin_amdgcn_global_load_lds((const __attribute__((address_space(1))) void*)g,
                                   (__attribute__((address_space(3))) void*)l, 16, 0, 0);
}

// ---------------------------------------------------------------------------
// K0: fused prep.
//  [0,2048)      : W_enc (2048x1024 fp32) -> WT (1024x2048 bf16, a-major)
//  [2048,2560)   : attn2p = hidden@W_hid + b_hid + b_enc (k-split 8, atomic)
//  [2560,27648)  : enc fp32 -> encB bf16 row-major (only launched in path A)
__global__ __launch_bounds__(256) void prep_kernel(
    const float* __restrict__ W, u16* __restrict__ WT,
    const float* __restrict__ hidden, const float* __restrict__ W_hid,
    const float* __restrict__ b_hid, const float* __restrict__ b_enc,
    float* __restrict__ attn2p,
    const float* __restrict__ enc, u16* __restrict__ encB) {
  int t = threadIdx.x;
  if (blockIdx.x < 2048) {
    __shared__ float tile[32][33];
    int id = blockIdx.x;
    int kb = (id & 63) * 32, ab = (id >> 6) * 32;
    int r = t >> 3, c = (t & 7) * 4;
    float4 v = *(const float4*)&W[(size_t)(kb + r) * A_DIM + ab + c];
    tile[r][c] = v.x; tile[r][c + 1] = v.y; tile[r][c + 2] = v.z; tile[r][c + 3] = v.w;
    __syncthreads();
    ushort4 o;
    o.x = f2b(tile[c + 0][r]);
    o.y = f2b(tile[c + 1][r]);
    o.z = f2b(tile[c + 2][r]);
    o.w = f2b(tile[c + 3][r]);
    *(ushort4*)&WT[(size_t)(ab + r) * F_DIM + kb + c] = o;
  } else if (blockIdx.x < 2560) {
    __shared__ float hl[8][128];
    int id = blockIdx.x - 2048;        // 512 blocks: 4 a-chunks x 16 b x 8 k
    int a  = (id & 3) * 256 + t;
    int b0 = ((id >> 2) & 15) * 8;
    int k0 = (id >> 6) * 128;
    {
      int j = t >> 5, kk = (t & 31) * 4;
      float4 v = *(const float4*)&hidden[(size_t)(b0 + j) * H_DIM + k0 + kk];
      hl[j][kk + 0] = v.x; hl[j][kk + 1] = v.y; hl[j][kk + 2] = v.z; hl[j][kk + 3] = v.w;
    }
    __syncthreads();
    float acc[8] = {0.f, 0.f, 0.f, 0.f, 0.f, 0.f, 0.f, 0.f};
    #pragma unroll 4
    for (int k = 0; k < 128; ++k) {
      float w = W_hid[(size_t)(k0 + k) * A_DIM + a];
      #pragma unroll
      for (int j = 0; j < 8; ++j) acc[j] = fmaf(hl[j][k], w, acc[j]);
    }
    if ((id >> 6) == 0) {
      float bias = b_hid[a] + b_enc[a];
      #pragma unroll
      for (int j = 0; j < 8; ++j) acc[j] += bias;
    }
    #pragma unroll
    for (int j = 0; j < 8; ++j) atomicAdd(&attn2p[(size_t)(b0 + j) * A_DIM + a], acc[j]);
  } else {
    // enc -> bf16: one block per row, thread t converts 8 floats.
    int r = blockIdx.x - 2560;
    const float4* sp = (const float4*)(enc + (size_t)r * F_DIM) + t * 2;
    float4 a = sp[0], b = sp[1];
    u32x4 w;
    w.x = f2b_pk(a.x, a.y); w.y = f2b_pk(a.z, a.w);
    w.z = f2b_pk(b.x, b.y); w.w = f2b_pk(b.z, b.w);
    *(u32x4*)(encB + (size_t)r * F_DIM + t * 8) = w;
  }
}

// ---------------------------------------------------------------------------
// K2a (path A): pure m201-structure GEMM + score. Both A (encB bf16) and B
// (WT bf16) staged via global_load_lds with pre-swizzled sources (T2; LDS
// dest linear). NO reg-staging, NO cvt in the loop -> arch VGPR well under
// the 128 cap (512-thread block: 256 unified regs/wave - 128 AGPR acc).
// Freed budget pays for the cross-phase B-fragment cache (bf0/bf1): LDS
// reads 32 -> 24 b128/wave/K-tile. 4 phases/K-tile, 16 MFMA each, setprio
// around MFMA (T5). Staging for tile T+1 issued p0/p1; single vmcnt(0) at
// p3 has ~2.5 phases of lead on L2/L3-resident data.
__global__ __launch_bounds__(512, 2) void gemm_score_a(
    const u16* __restrict__ encB, const u16* __restrict__ WT,
    const float* __restrict__ attn2p, const float* __restrict__ W_full,
    float* __restrict__ scores) {
  __shared__ __align__(16) u16 As[2 * 16384];   // 2 bufs x 256 x 64 bf16 = 64 KB
  __shared__ __align__(16) u16 Bs[2 * 16384];   // 64 KB

  int i = blockIdx.x;
  int g = i >> 5, r = i & 31;
  int y = r >> 3, gi = r & 7;
  int mt = g * 8 + gi;
  if (mt >= MTILES) return;              // uniform per-block: no barrier hazard
  int m0 = mt * 256, n0 = y * 256;
  int t = threadIdx.x;
  int lane = t & 63, wave = t >> 6;
  int wr = wave >> 2, wc = wave & 3;     // wave grid 2M x 4N
  int c16 = lane & 15, quad = lane >> 4;

  // staging: call s covers rows s*64 + (t>>3); source granule pre-swizzled
  // (g ^ row&7) so linear LDS dest == swizzled layout. Identical for A and B.
  const u16* agp = encB + (size_t)(m0 + (t >> 3)) * F_DIM + ((t & 7) ^ ((t >> 3) & 7)) * 8;
  const u16* bgp = WT   + (size_t)(n0 + (t >> 3)) * F_DIM + ((t & 7) ^ ((t >> 3) & 7)) * 8;

  // fragment read offsets (u16 elems); akey = row&7 == c16&7
  const int akey = c16 & 7;
  int gsw[2];
  gsw[0] = ((0 * 4 + quad) ^ akey) * 8;
  gsw[1] = ((1 * 4 + quad) ^ akey) * 8;
  const int aro = (wr * 128 + c16) * 64;
  const int bro = (wc * 64 + c16) * 64;

  f32x4 acc[8][4];
  #pragma unroll
  for (int mi = 0; mi < 8; ++mi)
    #pragma unroll
    for (int ni = 0; ni < 4; ++ni) acc[mi][ni] = (f32x4){0.f, 0.f, 0.f, 0.f};

  s16x8 af[4][2], bf0[2][2], bf1[2][2];

#define AGL(cb, kt_) do {                                                       \
    _Pragma("unroll")                                                           \
    for (int s_ = 0; s_ < 4; ++s_)                                              \
      gload_lds16(agp + (size_t)s_ * 64 * F_DIM + (size_t)(kt_) * 64,           \
                  As + (cb) * 16384 + s_ * 4096 + wave * 512);                  \
  } while (0)

#define BGL(cb, kt_) do {                                                       \
    _Pragma("unroll")                                                           \
    for (int s_ = 0; s_ < 4; ++s_)                                              \
      gload_lds16(bgp + (size_t)s_ * 64 * F_DIM + (size_t)(kt_) * 64,           \
                  Bs + (cb) * 16384 + s_ * 4096 + wave * 512);                  \
  } while (0)

#define DSRA(cb, mh)                                                            \
    _Pragma("unroll")                                                           \
    for (int i_ = 0; i_ < 4; ++i_)                                              \
      _Pragma("unroll")                                                         \
      for (int h_ = 0; h_ < 2; ++h_)                                            \
        af[i_][h_] = *(const s16x8*)&As[(cb) * 16384 + aro                      \
                                        + ((mh) * 4 + i_) * 1024 + gsw[h_]];

#define DSRB(BF, cb, nh)                                                        \
    _Pragma("unroll")                                                           \
    for (int j_ = 0; j_ < 2; ++j_)                                              \
      _Pragma("unroll")                                                         \
      for (int h_ = 0; h_ < 2; ++h_)                                            \
        BF[j_][h_] = *(const s16x8*)&Bs[(cb) * 16384 + bro                      \
                                        + ((nh) * 2 + j_) * 1024 + gsw[h_]];

#define PHTAIL(BF, mh, nh) do {                                                 \
    __builtin_amdgcn_s_barrier();                                               \
    asm volatile("s_waitcnt lgkmcnt(0)" ::: "memory");                          \
    __builtin_amdgcn_s_setprio(1);                                              \
    _Pragma("unroll")                                                           \
    for (int i_ = 0; i_ < 4; ++i_)                                              \
      _Pragma("unroll")                                                         \
      for (int j_ = 0; j_ < 2; ++j_)                                            \
        _Pragma("unroll")                                                       \
        for (int h_ = 0; h_ < 2; ++h_)                                          \
          acc[(mh) * 4 + i_][(nh) * 2 + j_] =                                   \
              __builtin_amdgcn_mfma_f32_16x16x32_bf16(                          \
                  af[i_][h_], BF[j_][h_],                                       \
                  acc[(mh) * 4 + i_][(nh) * 2 + j_], 0, 0, 0);                  \
    __builtin_amdgcn_s_setprio(0);                                              \
    __builtin_amdgcn_s_barrier();                                               \
  } while (0)

// Group T: MFMA on buf RB_, stage tile T+1 into WB_ (A at p0, B at p1).
#define GROUPA(T_, RB_, WB_) do {                                               \
    int kS_ = min((T_) + 1, 31);                                                \
    /* p0 */ DSRA(RB_, 0); DSRB(bf0, RB_, 0); AGL(WB_, kS_); PHTAIL(bf0, 0, 0);\
    /* p1 */ DSRB(bf1, RB_, 1); BGL(WB_, kS_);              PHTAIL(bf1, 0, 1); \
    /* p2 */ DSRA(RB_, 1);                                   PHTAIL(bf0, 1, 0);\
    /* p3 */ asm volatile("s_waitcnt vmcnt(0)" ::: "memory"); PHTAIL(bf1, 1, 1);\
  } while (0)

  // ---- prologue: buf0 <- tile 0 (A,B), drain, barrier.
  AGL(0, 0);
  BGL(0, 0);
  asm volatile("s_waitcnt vmcnt(0) lgkmcnt(0)" ::: "memory");
  __builtin_amdgcn_s_barrier();

  #pragma unroll 1
  for (int T = 0; T < 32; T += 2) {
    GROUPA(T,     0, 1);
    GROUPA(T + 1, 1, 0);
  }
#undef GROUPA
#undef PHTAIL
#undef DSRA
#undef DSRB
#undef BGL
#undef AGL

  // ---- epilogue: relu(attn1 + attn2)·W_full, 16-lane reduce, atomic score.
  int bfirst = m0 / LLEN;
  int bnd1 = (bfirst + 1) * LLEN, bnd2 = (bfirst + 2) * LLEN;
  int b1c = min(bfirst + 1, BATCH - 1), b2c = min(bfirst + 2, BATCH - 1);
  float wf[4], a2v0[4], a2v1[4], a2v2[4];
  #pragma unroll
  for (int ni = 0; ni < 4; ++ni) {
    int col = n0 + wc * 64 + ni * 16 + c16;
    wf[ni]   = W_full[col];
    a2v0[ni] = attn2p[(size_t)bfirst * A_DIM + col];
    a2v1[ni] = attn2p[(size_t)b1c * A_DIM + col];
    a2v2[ni] = attn2p[(size_t)b2c * A_DIM + col];
  }
  #pragma unroll
  for (int mi = 0; mi < 8; ++mi) {
    #pragma unroll
    for (int rr = 0; rr < 4; ++rr) {
      int row_g = m0 + wr * 128 + mi * 16 + quad * 4 + rr;
      float p = 0.f;
      #pragma unroll
      for (int ni = 0; ni < 4; ++ni) {
        float a2 = row_g >= bnd1 ? (row_g >= bnd2 ? a2v2[ni] : a2v1[ni]) : a2v0[ni];
        float v = acc[mi][ni][rr] + a2;
        v = fmaxf(v, 0.f);
        p = fmaf(v, wf[ni], p);
      }
      p += __shfl_xor(p, 1);
      p += __shfl_xor(p, 2);
      p += __shfl_xor(p, 4);
      p += __shfl_xor(p, 8);
      if (c16 == 0) atomicAdd(&scores[row_g], p);
    }
  }
}

// ---------------------------------------------------------------------------
// K2b (fallback, small workspace): the round-3 kernel verbatim (measured
// 182us, 120 VGPR, no spill). fp32-A reg-staging with ping-pong sets,
// write-first group order (the only order that fits the 128-VGPR cap).
__global__ __launch_bounds__(512, 2) void gemm_score_b(
    const float* __restrict__ enc, const u16* __restrict__ WT,
    const float* __restrict__ attn2p, const float* __restrict__ W_full,
    float* __restrict__ scores) {
  __shared__ __align__(16) u16 As[2 * 16384];
  __shared__ __align__(16) u16 Bs[2 * 16384];

  int i = blockIdx.x;
  int g = i >> 5, r = i & 31;
  int y = r >> 3, gi = r & 7;
  int mt = g * 8 + gi;
  if (mt >= MTILES) return;
  int m0 = mt * 256, n0 = y * 256;
  int t = threadIdx.x;
  int lane = t & 63, wave = t >> 6;
  int wr = wave >> 2, wc = wave & 3;
  int c16 = lane & 15, quad = lane >> 4;

  const float* aP = enc + (size_t)(m0 + (t >> 2)) * F_DIM + (t & 3) * 4;
  int awo[4];
  #pragma unroll
  for (int s = 0; s < 4; ++s)
    awo[s] = (t >> 2) * 64 + ((t & 3) & 1) * 4
           + (((s * 2 + ((t & 3) >> 1)) ^ ((t >> 2) & 7)) * 8);
  const u16* bgp = WT + (size_t)(n0 + (t >> 3)) * F_DIM + ((t & 7) ^ ((t >> 3) & 7)) * 8;

  const int akey = c16 & 7;
  int gsw[2];
  gsw[0] = ((0 * 4 + quad) ^ akey) * 8;
  gsw[1] = ((1 * 4 + quad) ^ akey) * 8;
  const int aro = (wr * 128 + c16) * 64;
  const int bro = (wc * 64 + c16) * 64;

  f32x4 acc[8][4];
  #pragma unroll
  for (int mi = 0; mi < 8; ++mi)
    #pragma unroll
    for (int ni = 0; ni < 4; ++ni) acc[mi][ni] = (f32x4){0.f, 0.f, 0.f, 0.f};

  s16x8 af[4][2], bf[2][2];
  float4 R0lo[4], R0hi[4], R1lo[4], R1hi[4];

#define ALD(RX, half, kt_) do {                                                 \
    const float* p_ = aP + (size_t)(half) * 128 * F_DIM + (kt_) * 64;           \
    RX[0] = *(const float4*)(p_);                                               \
    RX[1] = *(const float4*)(p_ + 16);                                          \
    RX[2] = *(const float4*)(p_ + 32);                                          \
    RX[3] = *(const float4*)(p_ + 48);                                          \
  } while (0)

#define AWR(RX, cb, half) do {                                                  \
    _Pragma("unroll")                                                           \
    for (int s_ = 0; s_ < 4; ++s_) {                                            \
      u32x2 w_; w_.x = f2b_pk(RX[s_].x, RX[s_].y);                              \
      w_.y = f2b_pk(RX[s_].z, RX[s_].w);                                        \
      *(u32x2*)&As[(cb) * 16384 + (half) * 8192 + awo[s_]] = w_;                \
    }                                                                           \
  } while (0)

#define BGL(cb, kt_) do {                                                       \
    _Pragma("unroll")                                                           \
    for (int s_ = 0; s_ < 4; ++s_)                                              \
      gload_lds16(bgp + (size_t)s_ * 64 * F_DIM + (size_t)(kt_) * 64,           \
                  Bs + (cb) * 16384 + s_ * 4096 + wave * 512);                  \
  } while (0)

#define DSRA(cb, mh)                                                            \
    _Pragma("unroll")                                                           \
    for (int i_ = 0; i_ < 4; ++i_)                                              \
      _Pragma("unroll")                                                         \
      for (int h_ = 0; h_ < 2; ++h_)                                            \
        af[i_][h_] = *(const s16x8*)&As[(cb) * 16384 + aro                      \
                                        + ((mh) * 4 + i_) * 1024 + gsw[h_]];

#define DSRB(cb, nh)                                                            \
    _Pragma("unroll")                                                           \
    for (int j_ = 0; j_ < 2; ++j_)                                              \
      _Pragma("unroll")                                                         \
      for (int h_ = 0; h_ < 2; ++h_)                                            \
        bf[j_][h_] = *(const s16x8*)&Bs[(cb) * 16384 + bro                      \
                                        + ((nh) * 2 + j_) * 1024 + gsw[h_]];

#define PHTAIL(mh, nh) do {                                                     \
    __builtin_amdgcn_s_barrier();                                               \
    asm volatile("s_waitcnt lgkmcnt(0)" ::: "memory");                          \
    __builtin_amdgcn_s_setprio(1);                                              \
    _Pragma("unroll")                                                           \
    for (int i_ = 0; i_ < 4; ++i_)                                              \
      _Pragma("unroll")                                                         \
      for (int j_ = 0; j_ < 2; ++j_)                                            \
        _Pragma("unroll")                                                       \
        for (int h_ = 0; h_ < 2; ++h_)                                          \
          acc[(mh) * 4 + i_][(nh) * 2 + j_] =                                   \
              __builtin_amdgcn_mfma_f32_16x16x32_bf16(                          \
                  af[i_][h_], bf[j_][h_],                                       \
                  acc[(mh) * 4 + i_][(nh) * 2 + j_], 0, 0, 0);                  \
    __builtin_amdgcn_s_setprio(0);                                               \
    __builtin_amdgcn_s_barrier();                                               \
  } while (0)

#define GROUP(T_, RB_, WB_, WLO_, WHI_, LLO_, LHI_) do {                        \
    int kB_ = min((T_) + 1, 31);                                                \
    int kA_ = min((T_) + 2, 31);                                                \
    /* p0 */ DSRA(RB_, 0); DSRB(RB_, 0); AWR(WLO_, WB_, 0); BGL(WB_, kB_);      \
    PHTAIL(0, 0);                                                               \
    /* p1 */ DSRB(RB_, 1); AWR(WHI_, WB_, 1); ALD(LLO_, 0, kA_);                \
    PHTAIL(0, 1);                                                               \
    /* p2 */ DSRA(RB_, 1); DSRB(RB_, 0); ALD(LHI_, 1, kA_);                     \
    PHTAIL(1, 0);                                                               \
    /* p3 */ DSRB(RB_, 1);                                                      \
    asm volatile("s_waitcnt vmcnt(8)" ::: "memory");                            \
    PHTAIL(1, 1);                                                               \
  } while (0)

  ALD(R0lo, 0, 0);
  ALD(R0hi, 1, 0);
  BGL(0, 0);
  asm volatile("s_waitcnt vmcnt(4)" ::: "memory");
  AWR(R0lo, 0, 0);
  AWR(R0hi, 0, 1);
  ALD(R1lo, 0, 1);
  ALD(R1hi, 1, 1);
  asm volatile("s_waitcnt vmcnt(8) lgkmcnt(0)" ::: "memory");
  __builtin_amdgcn_s_barrier();

  #pragma unroll 1
  for (int T = 0; T < 32; T += 2) {
    GROUP(T,     0, 1, R1lo, R1hi, R0lo, R0hi);
    GROUP(T + 1, 1, 0, R0lo, R0hi, R1lo, R1hi);
  }
#undef GROUP
#undef PHTAIL
#undef DSRA
#undef DSRB
#undef BGL
#undef AWR
#undef ALD

  int bfirst = m0 / LLEN;
  int bnd1 = (bfirst + 1) * LLEN, bnd2 = (bfirst + 2) * LLEN;
  int b1c = min(bfirst + 1, BATCH - 1), b2c = min(bfirst + 2, BATCH - 1);
  float wf[4], a2v0[4], a2v1[4], a2v2[4];
  #pragma unroll
  for (int ni = 0; ni < 4; ++ni) {
    int col = n0 + wc * 64 + ni * 16 + c16;
    wf[ni]   = W_full[col];
    a2v0[ni] = attn2p[(size_t)bfirst * A_DIM + col];
    a2v1[ni] = attn2p[(size_t)b1c * A_DIM + col];
    a2v2[ni] = attn2p[(size_t)b2c * A_DIM + col];
  }
  #pragma unroll
  for (int mi = 0; mi < 8; ++mi) {
    #pragma unroll
    for (int rr = 0; rr < 4; ++rr) {
      int row_g = m0 + wr * 128 + mi * 16 + quad * 4 + rr;
      float p = 0.f;
      #pragma unroll
      for (int ni = 0; ni < 4; ++ni) {
        float a2 = row_g >= bnd1 ? (row_g >= bnd2 ? a2v2[ni] : a2v1[ni]) : a2v0[ni];
        float v = acc[mi][ni][rr] + a2;
        v = fmaxf(v, 0.f);
        p = fmaf(v, wf[ni], p);
      }
      p += __shfl_xor(p, 1);
      p += __shfl_xor(p, 2);
      p += __shfl_xor(p, 4);
      p += __shfl_xor(p, 8);
      if (c16 == 0) atomicAdd(&scores[row_g], p);
    }
  }
}

// ---------------------------------------------------------------------------
// K4: fused softmax + context (unchanged from round 5).
__global__ __launch_bounds__(256) void context_kernel(
    const float* __restrict__ enc, const float* __restrict__ scores,
    float* __restrict__ alpha_out, float* __restrict__ out) {
  __shared__ float al[LLEN];
  __shared__ float red[8];
  __shared__ float4 part[4][64];
  int b = blockIdx.y, t = threadIdx.x;
  float s = (t < LLEN) ? scores[b * LLEN + t] : -3.0e38f;
  float m = s;
  #pragma unroll
  for (int o = 1; o <= 32; o <<= 1) m = fmaxf(m, __shfl_xor(m, o));
  if ((t & 63) == 0) red[t >> 6] = m;
  __syncthreads();
  m = fmaxf(fmaxf(red[0], red[1]), fmaxf(red[2], red[3]));
  float e = (t < LLEN) ? expf(s - m) : 0.f;
  float sum = e;
  #pragma unroll
  for (int o = 1; o <= 32; o <<= 1) sum += __shfl_xor(sum, o);
  if ((t & 63) == 0) red[4 + (t >> 6)] = sum;
  __syncthreads();
  sum = red[4] + red[5] + red[6] + red[7];
  float av = e / sum;
  if (t < LLEN) {
    al[t] = av;
    if (blockIdx.x == 0) alpha_out[b * LLEN + t] = av;
  }
  __syncthreads();
  int f4 = blockIdx.x * 64 + (t & 63);
  int lq = t >> 6;
  const float4* e4 = (const float4*)enc
                   + ((size_t)b * LLEN + lq * 49) * (F_DIM / 4) + f4;
  float4 acc = {0.f, 0.f, 0.f, 0.f};
  #pragma unroll 7
  for (int j = 0; j < 49; ++j) {
    float4 v = e4[(size_t)j * (F_DIM / 4)];
    float a = al[lq * 49 + j];
    acc.x = fmaf(v.x, a, acc.x);
    acc.y = fmaf(v.y, a, acc.y);
    acc.z = fmaf(v.z, a, acc.z);
    acc.w = fmaf(v.w, a, acc.w);
  }
  part[lq][t & 63] = acc;
  __syncthreads();
  if (t < 64) {
    float4 p0 = part[0][t], p1 = part[1][t], p2 = part[2][t], p3 = part[3][t];
    float4 sv;
    sv.x = (p0.x + p1.x) + (p2.x + p3.x);
    sv.y = (p0.y + p1.y) + (p2.y + p3.y);
    sv.z = (p0.z + p1.z) + (p2.z + p3.z);
    sv.w = (p0.w + p1.w) + (p2.w + p3.w);
    *(float4*)(out + (size_t)b * F_DIM + (size_t)(blockIdx.x * 64 + t) * 4) = sv;
  }
}

// ---------------------------------------------------------------------------
extern "C" void kernel_launch(void* const* d_in, const int* in_sizes, int n_in,
                              void* d_out, int out_size, void* d_ws, size_t ws_size,
                              hipStream_t stream) {
  const float* enc    = (const float*)d_in[0];
  const float* hidden = (const float*)d_in[1];
  const float* W_enc  = (const float*)d_in[2];
  const float* b_enc  = (const float*)d_in[3];
  const float* W_hid  = (const float*)d_in[4];
  const float* b_hid  = (const float*)d_in[5];
  const float* W_full = (const float*)d_in[6];
  float* out = (float*)d_out;
  float* alpha_out = out + (size_t)BATCH * F_DIM;

  const size_t wt_bytes   = (size_t)A_DIM * F_DIM * sizeof(u16);    // 4 MB
  const size_t a2_bytes   = (size_t)BATCH * A_DIM * sizeof(float);  // 512 KB
  const size_t sc_bytes   = (size_t)MROWS * sizeof(float);          // 100 KB
  const size_t encb_bytes = (size_t)MROWS * F_DIM * sizeof(u16);    // 102.8 MB
  char* ws = (char*)d_ws;
  u16*   WT     = (u16*)ws;
  float* attn2p = (float*)(ws + wt_bytes);
  float* scores = (float*)(ws + wt_bytes + a2_bytes);
  u16*   encB   = (u16*)(ws + wt_bytes + a2_bytes + sc_bytes);

  const bool bigws = ws_size >= wt_bytes + a2_bytes + sc_bytes + encb_bytes;

  hipMemsetAsync(attn2p, 0, a2_bytes + sc_bytes, stream);

  if (bigws) {
    // path A: prep also converts enc -> bf16; gemm is the pure m201 structure.
    prep_kernel<<<dim3(2048 + 512 + MROWS), 256, 0, stream>>>(
        W_enc, WT, hidden, W_hid, b_hid, b_enc, attn2p, enc, encB);
    gemm_score_a<<<dim3(416), 512, 0, stream>>>(encB, WT, attn2p, W_full, scores);
  } else {
    // path B: round-3 proven kernel (fp32-A reg-staging, 120 VGPR).
    prep_kernel<<<dim3(2048 + 512), 256, 0, stream>>>(
        W_enc, WT, hidden, W_hid, b_hid, b_enc, attn2p, enc, encB);
    gemm_score_b<<<dim3(416), 512, 0, stream>>>(enc, WT, attn2p, W_full, scores);
  }
  context_kernel<<<dim3(8, BATCH), 256, 0, stream>>>(enc, scores, alpha_out, out);
}